// Round 1
// baseline (14384.178 us; speedup 1.0000x reference)
//
#include <hip/hip_runtime.h>
#include <hip/hip_bf16.h>
#include <math.h>

#define B 32
#define S 512
#define W 8
#define CE 100       // CHAR_EMB
#define SE 100       // SUB_EMB
#define HD 200       // hidden per direction
#define G4 800       // 4*HD
#define IN2 200      // 2*CHAR_EMB
#define SUBV 100000
#define UNK 1
#define NL 4
#define SK (S - 2)   // 510
#define FEAT 500     // 2*HD + SE

// ---------------- K0: transpose [800][200] -> [200][800] ----------------
__global__ void transpose_k(const float* __restrict__ in, float* __restrict__ out) {
    int o = blockIdx.x * 256 + threadIdx.x;   // 160000 elements
    if (o >= IN2 * G4) return;
    int k = o / G4, g = o % G4;
    out[o] = in[g * 200 + k];
}

// ---------------- K1: embedding concat -> x[B][S][200] ----------------
__global__ void embed_k(const int* __restrict__ chars, const int* __restrict__ bichars,
                        const float* __restrict__ cw, const float* __restrict__ bw,
                        float* __restrict__ x) {
    int t = blockIdx.x * 256 + threadIdx.x;
    if (t >= B * S * IN2) return;
    int c = t % IN2;
    int row = t / IN2;
    float v;
    if (c < CE) v = cw[(size_t)chars[row] * CE + c];
    else        v = bw[(size_t)bichars[row] * CE + (c - CE)];
    x[t] = v;
}

// ---------------- K2: xg = x @ WihT + b (both directions) ----------------
// grid: (B*S/16, 2), block 256. Each block: 16 rows x all 800 gates.
__global__ void xg_k(const float* __restrict__ x,
                     const float* __restrict__ WihT_f, const float* __restrict__ bf,
                     const float* __restrict__ WihT_b, const float* __restrict__ bb,
                     float* __restrict__ xgf, float* __restrict__ xgb) {
    const int dir = blockIdx.y;
    const float* WT   = dir ? WihT_b : WihT_f;
    const float* bias = dir ? bb : bf;
    float* out        = dir ? xgb : xgf;
    int r0 = blockIdx.x * 16;
    __shared__ float xs[16][IN2];
    for (int i = threadIdx.x; i < 16 * IN2; i += 256) {
        xs[i / IN2][i % IN2] = x[(size_t)(r0 + i / IN2) * IN2 + i % IN2];
    }
    __syncthreads();
    float acc[4][16];
    for (int q = 0; q < 4; q++)
        for (int r = 0; r < 16; r++) acc[q][r] = 0.f;
    int tid = threadIdx.x;
    for (int k = 0; k < IN2; k++) {
        const float* wrow = WT + (size_t)k * G4;
        float w0 = wrow[tid];
        float w1 = wrow[tid + 256];
        float w2 = wrow[tid + 512];
        float w3 = (tid < 32) ? wrow[tid + 768] : 0.f;
        for (int r = 0; r < 16; r++) {
            float xv = xs[r][k];
            acc[0][r] += w0 * xv;
            acc[1][r] += w1 * xv;
            acc[2][r] += w2 * xv;
            acc[3][r] += w3 * xv;
        }
    }
    for (int q = 0; q < 4; q++) {
        int g = tid + q * 256;
        if (g < G4) {
            float bv = bias[g];
            for (int r = 0; r < 16; r++)
                out[(size_t)(r0 + r) * G4 + g] = acc[q][r] + bv;
        }
    }
}

// ---------------- K3: LSTM recurrence, one block per (dir, batch) chain ----
__global__ void lstm_k(const float* __restrict__ xgf, const float* __restrict__ xgb,
                       const float* __restrict__ WhhT_f, const float* __restrict__ WhhT_b,
                       float* __restrict__ hf, float* __restrict__ hb) {
    int bi = blockIdx.x;                 // 0..63
    int dir = bi >> 5;
    int b = bi & 31;
    const float* xg = dir ? xgb : xgf;
    const float* WT = dir ? WhhT_b : WhhT_f;
    float* hout     = dir ? hb : hf;
    __shared__ float hs[HD];
    __shared__ float gs[G4];
    int tid = threadIdx.x;
    if (tid < HD) hs[tid] = 0.f;
    float c = 0.f;                       // owned by threads tid < HD
    __syncthreads();
    for (int s = 0; s < S; s++) {
        int t = dir ? (S - 1 - s) : s;
        const float* xgrow = xg + ((size_t)b * S + t) * G4;
        float a0 = xgrow[tid];
        float a1 = xgrow[tid + 256];
        float a2 = xgrow[tid + 512];
        float a3 = (tid < 32) ? xgrow[tid + 768] : 0.f;
        for (int k = 0; k < HD; k++) {
            float hv = hs[k];
            const float* wrow = WT + (size_t)k * G4;
            a0 += wrow[tid] * hv;
            a1 += wrow[tid + 256] * hv;
            a2 += wrow[tid + 512] * hv;
            if (tid < 32) a3 += wrow[tid + 768] * hv;
        }
        gs[tid] = a0;
        gs[tid + 256] = a1;
        gs[tid + 512] = a2;
        if (tid < 32) gs[tid + 768] = a3;
        __syncthreads();
        if (tid < HD) {
            float ig = 1.f / (1.f + expf(-gs[tid]));
            float fg = 1.f / (1.f + expf(-gs[HD + tid]));
            float gg = tanhf(gs[2 * HD + tid]);
            float og = 1.f / (1.f + expf(-gs[3 * HD + tid]));
            c = fg * c + ig * gg;
            float h = og * tanhf(c);
            hs[tid] = h;
            hout[((size_t)b * S + t) * HD + tid] = h;
        }
        __syncthreads();
    }
}

// ---------------- K4: span features + subword emb + FFN ----------------
// one wave (64 lanes) per (b,k,i) output row; block = 4 waves
__global__ void out_k(const int* __restrict__ subwords,
                      const float* __restrict__ pre_w, const float* __restrict__ sub_w,
                      const float* __restrict__ hf, const float* __restrict__ hb,
                      const float* __restrict__ ffn_w, const float* __restrict__ ffn_b,
                      float* __restrict__ out) {
    int wave = (blockIdx.x * 256 + threadIdx.x) >> 6;
    int lane = threadIdx.x & 63;
    if (wave >= B * SK * W) return;
    int i = wave % W;
    int bk = wave / W;
    int k = bk % SK;
    int b = bk / SK;
    int end = k + i;
    float vscale = (end <= S - 3) ? 1.f : 0.f;
    int e1 = min(end + 1, S - 1);
    int e2 = min(end + 2, S - 1);
    const float* hfb = hf + (size_t)b * S * HD;
    const float* hbb = hb + (size_t)b * S * HD;
    int sw = subwords[wave];
    int sw2 = (sw >= SUBV) ? UNK : sw;
    float acc0 = 0, acc1 = 0, acc2 = 0, acc3 = 0;
    for (int j = lane; j < FEAT; j += 64) {
        float fv;
        if (j < HD) {
            fv = (hfb[(size_t)e1 * HD + j] - hfb[(size_t)k * HD + j]) * vscale;
        } else if (j < 2 * HD) {
            int jj = j - HD;
            fv = (hbb[(size_t)(k + 1) * HD + jj] - hbb[(size_t)e2 * HD + jj]) * vscale;
        } else {
            int jj = j - 2 * HD;
            fv = pre_w[(size_t)sw * SE + jj] + sub_w[(size_t)sw2 * SE + jj];
        }
        acc0 += ffn_w[j] * fv;
        acc1 += ffn_w[FEAT + j] * fv;
        acc2 += ffn_w[2 * FEAT + j] * fv;
        acc3 += ffn_w[3 * FEAT + j] * fv;
    }
    for (int off = 32; off; off >>= 1) {
        acc0 += __shfl_down(acc0, off);
        acc1 += __shfl_down(acc1, off);
        acc2 += __shfl_down(acc2, off);
        acc3 += __shfl_down(acc3, off);
    }
    if (lane == 0) {
        float* o = out + (size_t)wave * NL;
        o[0] = acc0 + ffn_b[0];
        o[1] = acc1 + ffn_b[1];
        o[2] = acc2 + ffn_b[2];
        o[3] = acc3 + ffn_b[3];
    }
}

extern "C" void kernel_launch(void* const* d_in, const int* in_sizes, int n_in,
                              void* d_out, int out_size, void* d_ws, size_t ws_size,
                              hipStream_t stream) {
    const int*   chars    = (const int*)d_in[0];
    const int*   bichars  = (const int*)d_in[1];
    const int*   subwords = (const int*)d_in[2];
    const float* cw    = (const float*)d_in[3];
    const float* bw    = (const float*)d_in[4];
    const float* subw  = (const float*)d_in[5];
    const float* prew  = (const float*)d_in[6];
    const float* Wih_f = (const float*)d_in[7];
    const float* Whh_f = (const float*)d_in[8];
    const float* b_f   = (const float*)d_in[9];
    const float* Wih_b = (const float*)d_in[10];
    const float* Whh_b = (const float*)d_in[11];
    const float* b_b   = (const float*)d_in[12];
    const float* ffn_w = (const float*)d_in[13];
    const float* ffn_b = (const float*)d_in[14];
    float* out = (float*)d_out;

    float* ws = (float*)d_ws;
    float* WihT_f = ws;                      // 160000 floats each
    float* WihT_b = WihT_f + 160000;
    float* WhhT_f = WihT_b + 160000;
    float* WhhT_b = WhhT_f + 160000;
    float* x   = WhhT_b + 160000;            // 3,276,800
    float* xgf = x + 3276800;                // 13,107,200
    float* xgb = xgf + 13107200;             // 13,107,200
    float* hf  = xgb + 13107200;             // 3,276,800
    float* hb  = hf + 3276800;               // 3,276,800

    transpose_k<<<625, 256, 0, stream>>>(Wih_f, WihT_f);
    transpose_k<<<625, 256, 0, stream>>>(Wih_b, WihT_b);
    transpose_k<<<625, 256, 0, stream>>>(Whh_f, WhhT_f);
    transpose_k<<<625, 256, 0, stream>>>(Whh_b, WhhT_b);
    embed_k<<<(B * S * IN2 + 255) / 256, 256, 0, stream>>>(chars, bichars, cw, bw, x);
    xg_k<<<dim3(B * S / 16, 2), 256, 0, stream>>>(x, WihT_f, b_f, WihT_b, b_b, xgf, xgb);
    lstm_k<<<64, 256, 0, stream>>>(xgf, xgb, WhhT_f, WhhT_b, hf, hb);
    out_k<<<(B * SK * W) / 4, 256, 0, stream>>>(subwords, prew, subw, hf, hb, ffn_w, ffn_b, out);
}

// Round 2
// 7817.856 us; speedup vs baseline: 1.8399x; 1.8399x over previous
//
#include <hip/hip_runtime.h>
#include <hip/hip_bf16.h>
#include <math.h>

#define B 32
#define S 512
#define W 8
#define CE 100       // CHAR_EMB
#define SE 100       // SUB_EMB
#define HD 200       // hidden per direction
#define G4 800       // 4*HD
#define IN2 200      // 2*CHAR_EMB
#define SUBV 100000
#define UNK 1
#define NL 4
#define SK (S - 2)   // 510
#define FEAT 500     // 2*HD + SE

// ---------------- K0: transpose [800][200] -> [200][800] ----------------
__global__ void transpose_k(const float* __restrict__ in, float* __restrict__ out) {
    int o = blockIdx.x * 256 + threadIdx.x;   // 160000 elements
    if (o >= IN2 * G4) return;
    int k = o / G4, g = o % G4;
    out[o] = in[g * 200 + k];
}

// ---------------- K1: embedding concat -> x[B][S][200] ----------------
__global__ void embed_k(const int* __restrict__ chars, const int* __restrict__ bichars,
                        const float* __restrict__ cw, const float* __restrict__ bw,
                        float* __restrict__ x) {
    int t = blockIdx.x * 256 + threadIdx.x;
    if (t >= B * S * IN2) return;
    int c = t % IN2;
    int row = t / IN2;
    float v;
    if (c < CE) v = cw[(size_t)chars[row] * CE + c];
    else        v = bw[(size_t)bichars[row] * CE + (c - CE)];
    x[t] = v;
}

// ---------------- K2: xg = x @ WihT + b (both directions) ----------------
__global__ void xg_k(const float* __restrict__ x,
                     const float* __restrict__ WihT_f, const float* __restrict__ bf,
                     const float* __restrict__ WihT_b, const float* __restrict__ bb,
                     float* __restrict__ xgf, float* __restrict__ xgb) {
    const int dir = blockIdx.y;
    const float* WT   = dir ? WihT_b : WihT_f;
    const float* bias = dir ? bb : bf;
    float* out        = dir ? xgb : xgf;
    int r0 = blockIdx.x * 16;
    __shared__ float xs[16][IN2];
    for (int i = threadIdx.x; i < 16 * IN2; i += 256) {
        xs[i / IN2][i % IN2] = x[(size_t)(r0 + i / IN2) * IN2 + i % IN2];
    }
    __syncthreads();
    float acc[4][16];
    for (int q = 0; q < 4; q++)
        for (int r = 0; r < 16; r++) acc[q][r] = 0.f;
    int tid = threadIdx.x;
    for (int k = 0; k < IN2; k++) {
        const float* wrow = WT + (size_t)k * G4;
        float w0 = wrow[tid];
        float w1 = wrow[tid + 256];
        float w2 = wrow[tid + 512];
        float w3 = (tid < 32) ? wrow[tid + 768] : 0.f;
        for (int r = 0; r < 16; r++) {
            float xv = xs[r][k];
            acc[0][r] += w0 * xv;
            acc[1][r] += w1 * xv;
            acc[2][r] += w2 * xv;
            acc[3][r] += w3 * xv;
        }
    }
    for (int q = 0; q < 4; q++) {
        int g = tid + q * 256;
        if (g < G4) {
            float bv = bias[g];
            for (int r = 0; r < 16; r++)
                out[(size_t)(r0 + r) * G4 + g] = acc[q][r] + bv;
        }
    }
}

// ---------------- K3: LSTM recurrence, 4 slice-blocks per (dir,batch) chain
// grid = 256 blocks (64 chains x 4 slices), block = 1024 threads.
// Slice owns 50 hidden units; weights register-resident:
//   thread t: c = t>>2 (gate-column 0..199, active c<200), p = t&3 (k-quarter)
//   holds Whh[g_glob][50p..50p+49] (50 floats). h exchange via hout rows with
//   agent-scope atomics + per-chain counter flag.
__global__ __launch_bounds__(1024, 4)
void lstm_k(const float* __restrict__ xgf, const float* __restrict__ xgb,
            const float* __restrict__ Whh_f, const float* __restrict__ Whh_b,
            float* __restrict__ hf, float* __restrict__ hb, int* __restrict__ ctr) {
    int blk = blockIdx.x;
    int chain = blk >> 2, slice = blk & 3;
    int dir = chain >> 5, b = chain & 31;
    const float* xg  = dir ? xgb : xgf;
    const float* Whh = dir ? Whh_b : Whh_f;
    float* hout      = dir ? hb : hf;
    int t = threadIdx.x;
    int c = t >> 2;          // gate column within slice: q*50+jj
    int p = t & 3;           // k-quarter
    bool active = (c < 200);
    int q = c / 50, jj = c % 50;
    int g_glob = q * 200 + slice * 50 + jj;   // row in Whh [800][200]

    float2 w[25];
    if (active) {
        const float2* wp = (const float2*)(Whh + (size_t)g_glob * HD + 50 * p);
        #pragma unroll
        for (int i = 0; i < 25; i++) w[i] = wp[i];
    }

    __shared__ float hs[HD];
    __shared__ float gbuf[HD];
    if (t < HD) hs[t] = 0.f;
    float cst = 0.f;                       // c-state, owned by t<50
    int* myctr = ctr + chain;
    __syncthreads();

    for (int s = 0; s < S; s++) {
        int ts = dir ? (S - 1 - s) : s;
        float acc0 = 0.f, acc1 = 0.f;
        if (active) {
            const float2* hp = (const float2*)(hs + 50 * p);
            #pragma unroll
            for (int i = 0; i < 25; i += 2) {
                float2 hv = hp[i];
                acc0 += w[i].x * hv.x + w[i].y * hv.y;
            }
            #pragma unroll
            for (int i = 1; i < 25; i += 2) {
                float2 hv = hp[i];
                acc1 += w[i].x * hv.x + w[i].y * hv.y;
            }
        }
        float acc = acc0 + acc1;
        acc += __shfl_xor(acc, 1);
        acc += __shfl_xor(acc, 2);
        if (active && p == 0) {
            float xgv = xg[((size_t)b * S + ts) * G4 + g_glob];
            gbuf[c] = acc + xgv;
        }
        __syncthreads();
        if (t < 50) {
            float ig = 1.f / (1.f + expf(-gbuf[t]));
            float fg = 1.f / (1.f + expf(-gbuf[50 + t]));
            float gg = tanhf(gbuf[100 + t]);
            float og = 1.f / (1.f + expf(-gbuf[150 + t]));
            cst = fg * cst + ig * gg;
            float h = og * tanhf(cst);
            __hip_atomic_store(&hout[((size_t)b * S + ts) * HD + slice * 50 + t], h,
                               __ATOMIC_RELAXED, __HIP_MEMORY_SCOPE_AGENT);
        }
        __syncthreads();   // all h stores issued+drained before flag
        if (t == 0) {
            __threadfence();
            __hip_atomic_fetch_add(myctr, 1, __ATOMIC_RELEASE, __HIP_MEMORY_SCOPE_AGENT);
            int target = 4 * (s + 1);
            while (__hip_atomic_load(myctr, __ATOMIC_ACQUIRE, __HIP_MEMORY_SCOPE_AGENT) < target) {}
        }
        __syncthreads();
        if (t < HD) {
            hs[t] = __hip_atomic_load(&hout[((size_t)b * S + ts) * HD + t],
                                      __ATOMIC_RELAXED, __HIP_MEMORY_SCOPE_AGENT);
        }
        __syncthreads();
    }
}

// ---------------- K4: span features + subword emb + FFN ----------------
__global__ void out_k(const int* __restrict__ subwords,
                      const float* __restrict__ pre_w, const float* __restrict__ sub_w,
                      const float* __restrict__ hf, const float* __restrict__ hb,
                      const float* __restrict__ ffn_w, const float* __restrict__ ffn_b,
                      float* __restrict__ out) {
    int wave = (blockIdx.x * 256 + threadIdx.x) >> 6;
    int lane = threadIdx.x & 63;
    if (wave >= B * SK * W) return;
    int i = wave % W;
    int bk = wave / W;
    int k = bk % SK;
    int b = bk / SK;
    int end = k + i;
    float vscale = (end <= S - 3) ? 1.f : 0.f;
    int e1 = min(end + 1, S - 1);
    int e2 = min(end + 2, S - 1);
    const float* hfb = hf + (size_t)b * S * HD;
    const float* hbb = hb + (size_t)b * S * HD;
    int sw = subwords[wave];
    int sw2 = (sw >= SUBV) ? UNK : sw;
    float acc0 = 0, acc1 = 0, acc2 = 0, acc3 = 0;
    for (int j = lane; j < FEAT; j += 64) {
        float fv;
        if (j < HD) {
            fv = (hfb[(size_t)e1 * HD + j] - hfb[(size_t)k * HD + j]) * vscale;
        } else if (j < 2 * HD) {
            int jj = j - HD;
            fv = (hbb[(size_t)(k + 1) * HD + jj] - hbb[(size_t)e2 * HD + jj]) * vscale;
        } else {
            int jj = j - 2 * HD;
            fv = pre_w[(size_t)sw * SE + jj] + sub_w[(size_t)sw2 * SE + jj];
        }
        acc0 += ffn_w[j] * fv;
        acc1 += ffn_w[FEAT + j] * fv;
        acc2 += ffn_w[2 * FEAT + j] * fv;
        acc3 += ffn_w[3 * FEAT + j] * fv;
    }
    for (int off = 32; off; off >>= 1) {
        acc0 += __shfl_down(acc0, off);
        acc1 += __shfl_down(acc1, off);
        acc2 += __shfl_down(acc2, off);
        acc3 += __shfl_down(acc3, off);
    }
    if (lane == 0) {
        float* o = out + (size_t)wave * NL;
        o[0] = acc0 + ffn_b[0];
        o[1] = acc1 + ffn_b[1];
        o[2] = acc2 + ffn_b[2];
        o[3] = acc3 + ffn_b[3];
    }
}

extern "C" void kernel_launch(void* const* d_in, const int* in_sizes, int n_in,
                              void* d_out, int out_size, void* d_ws, size_t ws_size,
                              hipStream_t stream) {
    const int*   chars    = (const int*)d_in[0];
    const int*   bichars  = (const int*)d_in[1];
    const int*   subwords = (const int*)d_in[2];
    const float* cw    = (const float*)d_in[3];
    const float* bw    = (const float*)d_in[4];
    const float* subw  = (const float*)d_in[5];
    const float* prew  = (const float*)d_in[6];
    const float* Wih_f = (const float*)d_in[7];
    const float* Whh_f = (const float*)d_in[8];
    const float* b_f   = (const float*)d_in[9];
    const float* Wih_b = (const float*)d_in[10];
    const float* Whh_b = (const float*)d_in[11];
    const float* b_b   = (const float*)d_in[12];
    const float* ffn_w = (const float*)d_in[13];
    const float* ffn_b = (const float*)d_in[14];
    float* out = (float*)d_out;

    float* ws = (float*)d_ws;
    float* WihT_f = ws;                      // 160000 floats each
    float* WihT_b = WihT_f + 160000;
    float* x   = WihT_b + 160000;            // 3,276,800
    float* xgf = x + 3276800;                // 13,107,200
    float* xgb = xgf + 13107200;             // 13,107,200
    float* hf  = xgb + 13107200;             // 3,276,800
    float* hb  = hf + 3276800;               // 3,276,800
    int*   ctr = (int*)(hb + 3276800);       // 64 ints

    hipMemsetAsync(ctr, 0, 64 * sizeof(int), stream);
    transpose_k<<<625, 256, 0, stream>>>(Wih_f, WihT_f);
    transpose_k<<<625, 256, 0, stream>>>(Wih_b, WihT_b);
    embed_k<<<(B * S * IN2 + 255) / 256, 256, 0, stream>>>(chars, bichars, cw, bw, x);
    xg_k<<<dim3(B * S / 16, 2), 256, 0, stream>>>(x, WihT_f, b_f, WihT_b, b_b, xgf, xgb);
    lstm_k<<<256, 1024, 0, stream>>>(xgf, xgb, Whh_f, Whh_b, hf, hb, ctr);
    out_k<<<(B * SK * W) / 4, 256, 0, stream>>>(subwords, prew, subw, hf, hb, ffn_w, ffn_b, out);
}

// Round 3
// 5413.681 us; speedup vs baseline: 2.6570x; 1.4441x over previous
//
#include <hip/hip_runtime.h>
#include <hip/hip_bf16.h>
#include <math.h>

#define B 32
#define S 512
#define W 8
#define CE 100       // CHAR_EMB
#define SE 100       // SUB_EMB
#define HD 200       // hidden per direction
#define G4 800       // 4*HD
#define IN2 200      // 2*CHAR_EMB
#define SUBV 100000
#define UNK 1
#define NL 4
#define SK (S - 2)   // 510
#define FEAT 500     // 2*HD + SE

__device__ __forceinline__ float fsig(float x) {
    return 1.f / (1.f + __expf(-x));
}
__device__ __forceinline__ float ftanh(float x) {
    // overflow-safe: e in (0,1]
    float e = __expf(-2.f * fabsf(x));
    float r = (1.f - e) / (1.f + e);
    return copysignf(r, x);
}

// ---------------- K0: transpose [800][200] -> [200][800] ----------------
__global__ void transpose_k(const float* __restrict__ in, float* __restrict__ out) {
    int o = blockIdx.x * 256 + threadIdx.x;   // 160000 elements
    if (o >= IN2 * G4) return;
    int k = o / G4, g = o % G4;
    out[o] = in[g * 200 + k];
}

// ---------------- K1: embedding concat -> x[B][S][200] ----------------
__global__ void embed_k(const int* __restrict__ chars, const int* __restrict__ bichars,
                        const float* __restrict__ cw, const float* __restrict__ bw,
                        float* __restrict__ x) {
    int t = blockIdx.x * 256 + threadIdx.x;
    if (t >= B * S * IN2) return;
    int c = t % IN2;
    int row = t / IN2;
    float v;
    if (c < CE) v = cw[(size_t)chars[row] * CE + c];
    else        v = bw[(size_t)bichars[row] * CE + (c - CE)];
    x[t] = v;
}

// ---------------- K2: xg = x @ WihT + b (both directions) ----------------
__global__ void xg_k(const float* __restrict__ x,
                     const float* __restrict__ WihT_f, const float* __restrict__ bf,
                     const float* __restrict__ WihT_b, const float* __restrict__ bb,
                     float* __restrict__ xgf, float* __restrict__ xgb) {
    const int dir = blockIdx.y;
    const float* WT   = dir ? WihT_b : WihT_f;
    const float* bias = dir ? bb : bf;
    float* out        = dir ? xgb : xgf;
    int r0 = blockIdx.x * 16;
    __shared__ float xs[16][IN2];
    for (int i = threadIdx.x; i < 16 * IN2; i += 256) {
        xs[i / IN2][i % IN2] = x[(size_t)(r0 + i / IN2) * IN2 + i % IN2];
    }
    __syncthreads();
    float acc[4][16];
    for (int q = 0; q < 4; q++)
        for (int r = 0; r < 16; r++) acc[q][r] = 0.f;
    int tid = threadIdx.x;
    for (int k = 0; k < IN2; k++) {
        const float* wrow = WT + (size_t)k * G4;
        float w0 = wrow[tid];
        float w1 = wrow[tid + 256];
        float w2 = wrow[tid + 512];
        float w3 = (tid < 32) ? wrow[tid + 768] : 0.f;
        for (int r = 0; r < 16; r++) {
            float xv = xs[r][k];
            acc[0][r] += w0 * xv;
            acc[1][r] += w1 * xv;
            acc[2][r] += w2 * xv;
            acc[3][r] += w3 * xv;
        }
    }
    for (int q = 0; q < 4; q++) {
        int g = tid + q * 256;
        if (g < G4) {
            float bv = bias[g];
            for (int r = 0; r < 16; r++)
                out[(size_t)(r0 + r) * G4 + g] = acc[q][r] + bv;
        }
    }
}

// ---------------- K3: LSTM recurrence, 4 slice-blocks per (dir,batch) chain
// grid = 256 blocks (64 chains x 4 slices), block = 1024 threads.
// Weights held in NAMED scalar registers (w0..w24, float2 each = 50 floats):
//   thread t: c = t>>2 (gate-col 0..255, active c<200), p = t&3 (k-quarter).
// h exchange between sibling slice-blocks via agent-scope atomics on hout
// + one padded counter per chain.
__global__ __launch_bounds__(1024, 4)
void lstm_k(const float* __restrict__ xgf, const float* __restrict__ xgb,
            const float* __restrict__ Whh_f, const float* __restrict__ Whh_b,
            float* __restrict__ hf, float* __restrict__ hb, int* __restrict__ ctr) {
    int blk = blockIdx.x;
    int chain = blk >> 2, slice = blk & 3;
    int dir = chain >> 5, b = chain & 31;
    const float* xg  = dir ? xgb : xgf;
    const float* Whh = dir ? Whh_b : Whh_f;
    float* hout      = dir ? hb : hf;
    int t = threadIdx.x;
    int c = t >> 2;          // gate column within slice
    int p = t & 3;           // k-quarter
    bool active = (c < 200);
    int cc = active ? c : 0; // inactive lanes alias row 0 (valid memory, result unused)
    int q = cc / 50, jj = cc % 50;
    int g_glob = q * 200 + slice * 50 + jj;   // row in Whh [800][200]

    const float2* wp = (const float2*)(Whh + (size_t)g_glob * HD + 50 * p);
#define W_LD(i) const float2 w##i = wp[i];
    W_LD(0)  W_LD(1)  W_LD(2)  W_LD(3)  W_LD(4)
    W_LD(5)  W_LD(6)  W_LD(7)  W_LD(8)  W_LD(9)
    W_LD(10) W_LD(11) W_LD(12) W_LD(13) W_LD(14)
    W_LD(15) W_LD(16) W_LD(17) W_LD(18) W_LD(19)
    W_LD(20) W_LD(21) W_LD(22) W_LD(23) W_LD(24)
#undef W_LD

    __shared__ float hs[HD];
    __shared__ float gbuf[HD];
    if (t < HD) hs[t] = 0.f;
    float cst = 0.f;                       // c-state, owned by t<50
    int* myctr = ctr + chain * 16;         // 64B-padded counter
    __syncthreads();

    for (int s = 0; s < S; s++) {
        int ts = dir ? (S - 1 - s) : s;
        float xgv = xg[((size_t)b * S + ts) * G4 + g_glob];
        const float2* hp = (const float2*)(hs + 50 * p);
        float acc0 = 0.f, acc1 = 0.f;
#define W_FMA(i, A) { const float2 hv = hp[i]; A = fmaf(w##i.y, hv.y, fmaf(w##i.x, hv.x, A)); }
        W_FMA(0,acc0)  W_FMA(1,acc1)  W_FMA(2,acc0)  W_FMA(3,acc1)  W_FMA(4,acc0)
        W_FMA(5,acc1)  W_FMA(6,acc0)  W_FMA(7,acc1)  W_FMA(8,acc0)  W_FMA(9,acc1)
        W_FMA(10,acc0) W_FMA(11,acc1) W_FMA(12,acc0) W_FMA(13,acc1) W_FMA(14,acc0)
        W_FMA(15,acc1) W_FMA(16,acc0) W_FMA(17,acc1) W_FMA(18,acc0) W_FMA(19,acc1)
        W_FMA(20,acc0) W_FMA(21,acc1) W_FMA(22,acc0) W_FMA(23,acc1) W_FMA(24,acc0)
#undef W_FMA
        float acc = acc0 + acc1;
        acc += __shfl_xor(acc, 1);
        acc += __shfl_xor(acc, 2);
        if (active && p == 0) gbuf[c] = acc + xgv;
        __syncthreads();
        if (t < 50) {
            float ig = fsig(gbuf[t]);
            float fg = fsig(gbuf[50 + t]);
            float gg = ftanh(gbuf[100 + t]);
            float og = fsig(gbuf[150 + t]);
            cst = fg * cst + ig * gg;
            float h = og * ftanh(cst);
            hs[slice * 50 + t] = h;        // own slice stays local
            __hip_atomic_store(&hout[((size_t)b * S + ts) * HD + slice * 50 + t], h,
                               __ATOMIC_RELAXED, __HIP_MEMORY_SCOPE_AGENT);
        }
        __syncthreads();   // all h stores drained (vmcnt) before flag
        if (t == 0) {
            __threadfence();
            __hip_atomic_fetch_add(myctr, 1, __ATOMIC_RELEASE, __HIP_MEMORY_SCOPE_AGENT);
            int target = 4 * (s + 1);
            while (__hip_atomic_load(myctr, __ATOMIC_ACQUIRE, __HIP_MEMORY_SCOPE_AGENT) < target) {}
        }
        __syncthreads();
        if (t < HD && (t >> 31 == 0)) {
            int sl = t / 50;
            if (sl != slice) {
                hs[t] = __hip_atomic_load(&hout[((size_t)b * S + ts) * HD + t],
                                          __ATOMIC_RELAXED, __HIP_MEMORY_SCOPE_AGENT);
            }
        }
        __syncthreads();
    }
}

// ---------------- K4: span features + subword emb + FFN ----------------
__global__ void out_k(const int* __restrict__ subwords,
                      const float* __restrict__ pre_w, const float* __restrict__ sub_w,
                      const float* __restrict__ hf, const float* __restrict__ hb,
                      const float* __restrict__ ffn_w, const float* __restrict__ ffn_b,
                      float* __restrict__ out) {
    int wave = (blockIdx.x * 256 + threadIdx.x) >> 6;
    int lane = threadIdx.x & 63;
    if (wave >= B * SK * W) return;
    int i = wave % W;
    int bk = wave / W;
    int k = bk % SK;
    int b = bk / SK;
    int end = k + i;
    float vscale = (end <= S - 3) ? 1.f : 0.f;
    int e1 = min(end + 1, S - 1);
    int e2 = min(end + 2, S - 1);
    const float* hfb = hf + (size_t)b * S * HD;
    const float* hbb = hb + (size_t)b * S * HD;
    int sw = subwords[wave];
    int sw2 = (sw >= SUBV) ? UNK : sw;
    float acc0 = 0, acc1 = 0, acc2 = 0, acc3 = 0;
    for (int j = lane; j < FEAT; j += 64) {
        float fv;
        if (j < HD) {
            fv = (hfb[(size_t)e1 * HD + j] - hfb[(size_t)k * HD + j]) * vscale;
        } else if (j < 2 * HD) {
            int jj = j - HD;
            fv = (hbb[(size_t)(k + 1) * HD + jj] - hbb[(size_t)e2 * HD + jj]) * vscale;
        } else {
            int jj = j - 2 * HD;
            fv = pre_w[(size_t)sw * SE + jj] + sub_w[(size_t)sw2 * SE + jj];
        }
        acc0 += ffn_w[j] * fv;
        acc1 += ffn_w[FEAT + j] * fv;
        acc2 += ffn_w[2 * FEAT + j] * fv;
        acc3 += ffn_w[3 * FEAT + j] * fv;
    }
    for (int off = 32; off; off >>= 1) {
        acc0 += __shfl_down(acc0, off);
        acc1 += __shfl_down(acc1, off);
        acc2 += __shfl_down(acc2, off);
        acc3 += __shfl_down(acc3, off);
    }
    if (lane == 0) {
        float* o = out + (size_t)wave * NL;
        o[0] = acc0 + ffn_b[0];
        o[1] = acc1 + ffn_b[1];
        o[2] = acc2 + ffn_b[2];
        o[3] = acc3 + ffn_b[3];
    }
}

extern "C" void kernel_launch(void* const* d_in, const int* in_sizes, int n_in,
                              void* d_out, int out_size, void* d_ws, size_t ws_size,
                              hipStream_t stream) {
    const int*   chars    = (const int*)d_in[0];
    const int*   bichars  = (const int*)d_in[1];
    const int*   subwords = (const int*)d_in[2];
    const float* cw    = (const float*)d_in[3];
    const float* bw    = (const float*)d_in[4];
    const float* subw  = (const float*)d_in[5];
    const float* prew  = (const float*)d_in[6];
    const float* Wih_f = (const float*)d_in[7];
    const float* Whh_f = (const float*)d_in[8];
    const float* b_f   = (const float*)d_in[9];
    const float* Wih_b = (const float*)d_in[10];
    const float* Whh_b = (const float*)d_in[11];
    const float* b_b   = (const float*)d_in[12];
    const float* ffn_w = (const float*)d_in[13];
    const float* ffn_b = (const float*)d_in[14];
    float* out = (float*)d_out;

    float* ws = (float*)d_ws;
    float* WihT_f = ws;                      // 160000 floats each
    float* WihT_b = WihT_f + 160000;
    float* x   = WihT_b + 160000;            // 3,276,800
    float* xgf = x + 3276800;                // 13,107,200
    float* xgb = xgf + 13107200;             // 13,107,200
    float* hf  = xgb + 13107200;             // 3,276,800
    float* hb  = hf + 3276800;               // 3,276,800
    int*   ctr = (int*)(hb + 3276800);       // 64 chains x 16 ints (64B padded)

    hipMemsetAsync(ctr, 0, 64 * 16 * sizeof(int), stream);
    transpose_k<<<625, 256, 0, stream>>>(Wih_f, WihT_f);
    transpose_k<<<625, 256, 0, stream>>>(Wih_b, WihT_b);
    embed_k<<<(B * S * IN2 + 255) / 256, 256, 0, stream>>>(chars, bichars, cw, bw, x);
    xg_k<<<dim3(B * S / 16, 2), 256, 0, stream>>>(x, WihT_f, b_f, WihT_b, b_b, xgf, xgb);
    lstm_k<<<256, 1024, 0, stream>>>(xgf, xgb, Whh_f, Whh_b, hf, hb, ctr);
    out_k<<<(B * SK * W) / 4, 256, 0, stream>>>(subwords, prew, subw, hf, hb, ffn_w, ffn_b, out);
}

// Round 5
// 3485.558 us; speedup vs baseline: 4.1268x; 1.5532x over previous
//
#include <hip/hip_runtime.h>
#include <hip/hip_bf16.h>
#include <math.h>

#define B 32
#define S 512
#define W 8
#define CE 100       // CHAR_EMB
#define SE 100       // SUB_EMB
#define HD 200       // hidden per direction
#define G4 800       // 4*HD
#define IN2 200      // 2*CHAR_EMB
#define SUBV 100000
#define UNK 1
#define NL 4
#define SK (S - 2)   // 510
#define FEAT 500     // 2*HD + SE

__device__ __forceinline__ float fsig(float x) {
    return 1.f / (1.f + __expf(-x));
}
__device__ __forceinline__ float ftanh(float x) {
    float e = __expf(-2.f * fabsf(x));   // e in (0,1], overflow-safe
    float r = (1.f - e) / (1.f + e);
    return copysignf(r, x);
}

// ---------------- K0: transpose [800][200] -> [200][800] ----------------
__global__ void transpose_k(const float* __restrict__ in, float* __restrict__ out) {
    int o = blockIdx.x * 256 + threadIdx.x;   // 160000 elements
    if (o >= IN2 * G4) return;
    int k = o / G4, g = o % G4;
    out[o] = in[g * 200 + k];
}

// ---------------- K1: embedding concat -> x[B][S][200] ----------------
__global__ void embed_k(const int* __restrict__ chars, const int* __restrict__ bichars,
                        const float* __restrict__ cw, const float* __restrict__ bw,
                        float* __restrict__ x) {
    int t = blockIdx.x * 256 + threadIdx.x;
    if (t >= B * S * IN2) return;
    int c = t % IN2;
    int row = t / IN2;
    float v;
    if (c < CE) v = cw[(size_t)chars[row] * CE + c];
    else        v = bw[(size_t)bichars[row] * CE + (c - CE)];
    x[t] = v;
}

// ---------------- K2: xg = x @ WihT + b (both directions) ----------------
__global__ void xg_k(const float* __restrict__ x,
                     const float* __restrict__ WihT_f, const float* __restrict__ bf,
                     const float* __restrict__ WihT_b, const float* __restrict__ bb,
                     float* __restrict__ xgf, float* __restrict__ xgb) {
    const int dir = blockIdx.y;
    const float* WT   = dir ? WihT_b : WihT_f;
    const float* bias = dir ? bb : bf;
    float* out        = dir ? xgb : xgf;
    int r0 = blockIdx.x * 16;
    __shared__ float xs[16][IN2];
    for (int i = threadIdx.x; i < 16 * IN2; i += 256) {
        xs[i / IN2][i % IN2] = x[(size_t)(r0 + i / IN2) * IN2 + i % IN2];
    }
    __syncthreads();
    float acc[4][16];
    for (int q = 0; q < 4; q++)
        for (int r = 0; r < 16; r++) acc[q][r] = 0.f;
    int tid = threadIdx.x;
    for (int k = 0; k < IN2; k++) {
        const float* wrow = WT + (size_t)k * G4;
        float w0 = wrow[tid];
        float w1 = wrow[tid + 256];
        float w2 = wrow[tid + 512];
        float w3 = (tid < 32) ? wrow[tid + 768] : 0.f;
        for (int r = 0; r < 16; r++) {
            float xv = xs[r][k];
            acc[0][r] += w0 * xv;
            acc[1][r] += w1 * xv;
            acc[2][r] += w2 * xv;
            acc[3][r] += w3 * xv;
        }
    }
    for (int q = 0; q < 4; q++) {
        int g = tid + q * 256;
        if (g < G4) {
            float bv = bias[g];
            for (int r = 0; r < 16; r++)
                out[(size_t)(r0 + r) * G4 + g] = acc[q][r] + bv;
        }
    }
}

// ---------------- K3: LSTM recurrence, chain-paired slice blocks ----------
// grid = 128 blocks = 2 dirs x 16 batch-pairs x 4 slices; block = 1024 thr.
// Each block owns a 50-hidden slice of TWO same-direction chains (b, b+16),
// which share the same Whh slice. Weights in named registers, made
// non-rematerializable via asm opacity. Phases alternate A/B so chain A's
// inter-block rendezvous latency hides under chain B's compute.
__global__ __launch_bounds__(1024, 4)
void lstm_k(const float* __restrict__ xgf, const float* __restrict__ xgb,
            const float* __restrict__ Whh_f, const float* __restrict__ Whh_b,
            float* __restrict__ hf, float* __restrict__ hb, int* __restrict__ ctr) {
    int blk = blockIdx.x;
    int pairid = blk >> 2, slice = blk & 3;
    int dir = pairid >> 4;
    int bA = pairid & 15;
    int bB = bA + 16;
    const float* xg  = dir ? xgb : xgf;
    const float* Whh = dir ? Whh_b : Whh_f;
    float* hout      = dir ? hb : hf;
    int t = threadIdx.x;
    int c = t >> 2;          // gate column within slice (active c<200)
    int p = t & 3;           // k-quarter
    bool active = (c < 200);
    int cc = active ? c : 0;
    int q = cc / 50, jj = cc % 50;
    int g_glob = q * 200 + slice * 50 + jj;   // row in Whh [800][200]

    const float2* wp = (const float2*)(Whh + (size_t)g_glob * HD + 50 * p);
#define W_LD(i) float2 w##i = wp[i];
    W_LD(0)  W_LD(1)  W_LD(2)  W_LD(3)  W_LD(4)
    W_LD(5)  W_LD(6)  W_LD(7)  W_LD(8)  W_LD(9)
    W_LD(10) W_LD(11) W_LD(12) W_LD(13) W_LD(14)
    W_LD(15) W_LD(16) W_LD(17) W_LD(18) W_LD(19)
    W_LD(20) W_LD(21) W_LD(22) W_LD(23) W_LD(24)
#undef W_LD
    // Opacity: values now come "from asm" -> compiler cannot re-load them
    // from memory inside the loop; they must stay in VGPRs.
    asm volatile("" : "+v"(w0.x),"+v"(w0.y),"+v"(w1.x),"+v"(w1.y),"+v"(w2.x),
                      "+v"(w2.y),"+v"(w3.x),"+v"(w3.y),"+v"(w4.x),"+v"(w4.y));
    asm volatile("" : "+v"(w5.x),"+v"(w5.y),"+v"(w6.x),"+v"(w6.y),"+v"(w7.x),
                      "+v"(w7.y),"+v"(w8.x),"+v"(w8.y),"+v"(w9.x),"+v"(w9.y));
    asm volatile("" : "+v"(w10.x),"+v"(w10.y),"+v"(w11.x),"+v"(w11.y),"+v"(w12.x),
                      "+v"(w12.y),"+v"(w13.x),"+v"(w13.y),"+v"(w14.x),"+v"(w14.y));
    asm volatile("" : "+v"(w15.x),"+v"(w15.y),"+v"(w16.x),"+v"(w16.y),"+v"(w17.x),
                      "+v"(w17.y),"+v"(w18.x),"+v"(w18.y),"+v"(w19.x),"+v"(w19.y));
    asm volatile("" : "+v"(w20.x),"+v"(w20.y),"+v"(w21.x),"+v"(w21.y),"+v"(w22.x),
                      "+v"(w22.y),"+v"(w23.x),"+v"(w23.y),"+v"(w24.x),"+v"(w24.y));

    __shared__ float hsA[HD];
    __shared__ float hsB[HD];
    __shared__ float gbuf[HD];
    if (t < HD) { hsA[t] = 0.f; hsB[t] = 0.f; }
    float cstA = 0.f, cstB = 0.f;          // c-state, owned by t<50
    int* ctrA = ctr + (dir * 32 + bA) * 16;
    int* ctrB = ctr + (dir * 32 + bB) * 16;
    __syncthreads();

#define W_FMA_ALL(hp)                                                          \
    { const float2* hq = (hp);                                                 \
      { const float2 h0=hq[0];  acc0 = fmaf(w0.y,h0.y,  fmaf(w0.x,h0.x,  acc0)); } \
      { const float2 h1=hq[1];  acc1 = fmaf(w1.y,h1.y,  fmaf(w1.x,h1.x,  acc1)); } \
      { const float2 h2=hq[2];  acc0 = fmaf(w2.y,h2.y,  fmaf(w2.x,h2.x,  acc0)); } \
      { const float2 h3=hq[3];  acc1 = fmaf(w3.y,h3.y,  fmaf(w3.x,h3.x,  acc1)); } \
      { const float2 h4=hq[4];  acc0 = fmaf(w4.y,h4.y,  fmaf(w4.x,h4.x,  acc0)); } \
      { const float2 h5=hq[5];  acc1 = fmaf(w5.y,h5.y,  fmaf(w5.x,h5.x,  acc1)); } \
      { const float2 h6=hq[6];  acc0 = fmaf(w6.y,h6.y,  fmaf(w6.x,h6.x,  acc0)); } \
      { const float2 h7=hq[7];  acc1 = fmaf(w7.y,h7.y,  fmaf(w7.x,h7.x,  acc1)); } \
      { const float2 h8=hq[8];  acc0 = fmaf(w8.y,h8.y,  fmaf(w8.x,h8.x,  acc0)); } \
      { const float2 h9=hq[9];  acc1 = fmaf(w9.y,h9.y,  fmaf(w9.x,h9.x,  acc1)); } \
      { const float2 ha=hq[10]; acc0 = fmaf(w10.y,ha.y, fmaf(w10.x,ha.x, acc0)); } \
      { const float2 hb_=hq[11];acc1 = fmaf(w11.y,hb_.y,fmaf(w11.x,hb_.x,acc1)); } \
      { const float2 hc=hq[12]; acc0 = fmaf(w12.y,hc.y, fmaf(w12.x,hc.x, acc0)); } \
      { const float2 hd=hq[13]; acc1 = fmaf(w13.y,hd.y, fmaf(w13.x,hd.x, acc1)); } \
      { const float2 he=hq[14]; acc0 = fmaf(w14.y,he.y, fmaf(w14.x,he.x, acc0)); } \
      { const float2 hf_=hq[15];acc1 = fmaf(w15.y,hf_.y,fmaf(w15.x,hf_.x,acc1)); } \
      { const float2 hg=hq[16]; acc0 = fmaf(w16.y,hg.y, fmaf(w16.x,hg.x, acc0)); } \
      { const float2 hh=hq[17]; acc1 = fmaf(w17.y,hh.y, fmaf(w17.x,hh.x, acc1)); } \
      { const float2 hi=hq[18]; acc0 = fmaf(w18.y,hi.y, fmaf(w18.x,hi.x, acc0)); } \
      { const float2 hj=hq[19]; acc1 = fmaf(w19.y,hj.y, fmaf(w19.x,hj.x, acc1)); } \
      { const float2 hk=hq[20]; acc0 = fmaf(w20.y,hk.y, fmaf(w20.x,hk.x, acc0)); } \
      { const float2 hl=hq[21]; acc1 = fmaf(w21.y,hl.y, fmaf(w21.x,hl.x, acc1)); } \
      { const float2 hm=hq[22]; acc0 = fmaf(w22.y,hm.y, fmaf(w22.x,hm.x, acc0)); } \
      { const float2 hn=hq[23]; acc1 = fmaf(w23.y,hn.y, fmaf(w23.x,hn.x, acc1)); } \
      { const float2 ho=hq[24]; acc0 = fmaf(w24.y,ho.y, fmaf(w24.x,ho.x, acc0)); } }

#define PHASE(hsX, cstX, bX, ctrX)                                             \
    {                                                                          \
        if (s > 0) {                                                           \
            if (t == 0) {                                                      \
                while (__hip_atomic_load(ctrX, __ATOMIC_RELAXED,               \
                                         __HIP_MEMORY_SCOPE_AGENT) < 4 * s) {} \
                __builtin_amdgcn_fence(__ATOMIC_ACQUIRE, "agent");             \
            }                                                                  \
            __syncthreads();                                                   \
            int tsp = dir ? (S - s) : (s - 1);                                 \
            if (t < HD) {                                                      \
                if (t / 50 != slice)                                           \
                    hsX[t] = __hip_atomic_load(                                \
                        &hout[((size_t)bX * S + tsp) * HD + t],                \
                        __ATOMIC_RELAXED, __HIP_MEMORY_SCOPE_AGENT);           \
            }                                                                  \
            __syncthreads();                                                   \
        }                                                                      \
        int ts = dir ? (S - 1 - s) : s;                                        \
        float acc0 = 0.f, acc1 = 0.f;                                          \
        W_FMA_ALL((const float2*)(hsX + 50 * p))                               \
        float acc = acc0 + acc1;                                               \
        acc += __shfl_xor(acc, 1);                                             \
        acc += __shfl_xor(acc, 2);                                             \
        if (active && p == 0)                                                  \
            gbuf[c] = acc + xg[((size_t)bX * S + ts) * G4 + g_glob];           \
        __syncthreads();                                                       \
        if (t < 50) {                                                          \
            float ig = fsig(gbuf[t]);                                          \
            float fg = fsig(gbuf[50 + t]);                                     \
            float gg = ftanh(gbuf[100 + t]);                                   \
            float og = fsig(gbuf[150 + t]);                                    \
            cstX = fg * cstX + ig * gg;                                        \
            float h = og * ftanh(cstX);                                        \
            hsX[slice * 50 + t] = h;                                           \
            __hip_atomic_store(&hout[((size_t)bX * S + ts) * HD + slice * 50 + t], \
                               h, __ATOMIC_RELAXED, __HIP_MEMORY_SCOPE_AGENT); \
        }                                                                      \
        __syncthreads();                                                       \
        if (t == 0)                                                            \
            __hip_atomic_fetch_add(ctrX, 1, __ATOMIC_RELEASE,                  \
                                   __HIP_MEMORY_SCOPE_AGENT);                  \
    }

    for (int s = 0; s < S; s++) {
        PHASE(hsA, cstA, bA, ctrA)
        PHASE(hsB, cstB, bB, ctrB)
    }
#undef PHASE
#undef W_FMA_ALL
}

// ---------------- K4: span features + subword emb + FFN ----------------
__global__ void out_k(const int* __restrict__ subwords,
                      const float* __restrict__ pre_w, const float* __restrict__ sub_w,
                      const float* __restrict__ hf, const float* __restrict__ hb,
                      const float* __restrict__ ffn_w, const float* __restrict__ ffn_b,
                      float* __restrict__ out) {
    int wave = (blockIdx.x * 256 + threadIdx.x) >> 6;
    int lane = threadIdx.x & 63;
    if (wave >= B * SK * W) return;
    int i = wave % W;
    int bk = wave / W;
    int k = bk % SK;
    int b = bk / SK;
    int end = k + i;
    float vscale = (end <= S - 3) ? 1.f : 0.f;
    int e1 = min(end + 1, S - 1);
    int e2 = min(end + 2, S - 1);
    const float* hfb = hf + (size_t)b * S * HD;
    const float* hbb = hb + (size_t)b * S * HD;
    int sw = subwords[wave];
    int sw2 = (sw >= SUBV) ? UNK : sw;
    float acc0 = 0, acc1 = 0, acc2 = 0, acc3 = 0;
    for (int j = lane; j < FEAT; j += 64) {
        float fv;
        if (j < HD) {
            fv = (hfb[(size_t)e1 * HD + j] - hfb[(size_t)k * HD + j]) * vscale;
        } else if (j < 2 * HD) {
            int jj = j - HD;
            fv = (hbb[(size_t)(k + 1) * HD + jj] - hbb[(size_t)e2 * HD + jj]) * vscale;
        } else {
            int jj = j - 2 * HD;
            fv = pre_w[(size_t)sw * SE + jj] + sub_w[(size_t)sw2 * SE + jj];
        }
        acc0 += ffn_w[j] * fv;
        acc1 += ffn_w[FEAT + j] * fv;
        acc2 += ffn_w[2 * FEAT + j] * fv;
        acc3 += ffn_w[3 * FEAT + j] * fv;
    }
    for (int off = 32; off; off >>= 1) {
        acc0 += __shfl_down(acc0, off);
        acc1 += __shfl_down(acc1, off);
        acc2 += __shfl_down(acc2, off);
        acc3 += __shfl_down(acc3, off);
    }
    if (lane == 0) {
        float* o = out + (size_t)wave * NL;
        o[0] = acc0 + ffn_b[0];
        o[1] = acc1 + ffn_b[1];
        o[2] = acc2 + ffn_b[2];
        o[3] = acc3 + ffn_b[3];
    }
}

extern "C" void kernel_launch(void* const* d_in, const int* in_sizes, int n_in,
                              void* d_out, int out_size, void* d_ws, size_t ws_size,
                              hipStream_t stream) {
    const int*   chars    = (const int*)d_in[0];
    const int*   bichars  = (const int*)d_in[1];
    const int*   subwords = (const int*)d_in[2];
    const float* cw    = (const float*)d_in[3];
    const float* bw    = (const float*)d_in[4];
    const float* subw  = (const float*)d_in[5];
    const float* prew  = (const float*)d_in[6];
    const float* Wih_f = (const float*)d_in[7];
    const float* Whh_f = (const float*)d_in[8];
    const float* b_f   = (const float*)d_in[9];
    const float* Wih_b = (const float*)d_in[10];
    const float* Whh_b = (const float*)d_in[11];
    const float* b_b   = (const float*)d_in[12];
    const float* ffn_w = (const float*)d_in[13];
    const float* ffn_b = (const float*)d_in[14];
    float* out = (float*)d_out;

    float* ws = (float*)d_ws;
    float* WihT_f = ws;                      // 160000 floats each
    float* WihT_b = WihT_f + 160000;
    float* x   = WihT_b + 160000;            // 3,276,800
    float* xgf = x + 3276800;                // 13,107,200
    float* xgb = xgf + 13107200;             // 13,107,200
    float* hf  = xgb + 13107200;             // 3,276,800
    float* hb  = hf + 3276800;               // 3,276,800
    int*   ctr = (int*)(hb + 3276800);       // 64 chains x 16 ints (64B padded)

    (void)hipMemsetAsync(ctr, 0, 64 * 16 * sizeof(int), stream);
    transpose_k<<<625, 256, 0, stream>>>(Wih_f, WihT_f);
    transpose_k<<<625, 256, 0, stream>>>(Wih_b, WihT_b);
    embed_k<<<(B * S * IN2 + 255) / 256, 256, 0, stream>>>(chars, bichars, cw, bw, x);
    xg_k<<<dim3(B * S / 16, 2), 256, 0, stream>>>(x, WihT_f, b_f, WihT_b, b_b, xgf, xgb);
    lstm_k<<<128, 1024, 0, stream>>>(xgf, xgb, Whh_f, Whh_b, hf, hb, ctr);
    out_k<<<(B * SK * W) / 4, 256, 0, stream>>>(subwords, prew, subw, hf, hb, ffn_w, ffn_b, out);
}